// Round 4
// baseline (125.547 us; speedup 1.0000x reference)
//
#include <hip/hip_runtime.h>
#include <hip/hip_bf16.h>

#define GENES 20000
#define TFS   1500
#define BATCH 128
#define NR    8            // gene ranges (2 per XCD-group)
#define GPR   2500         // genes per range
#define NBINS (NR * TFS)   // 12000
#define NB    64           // sort blocks (counting-sort partitions)

__device__ __forceinline__ unsigned short f32_to_bf16_rn(float f) {
    unsigned int u = __float_as_uint(f);
    u += 0x7fffu + ((u >> 16) & 1u);
    return (unsigned short)(u >> 16);
}

// ---------------- transpose x[B][G] (f32) -> xT[G][B] (bf16 bits) ----------------
__global__ void transpose_x_bf16(const float* __restrict__ x, unsigned short* __restrict__ xT) {
    __shared__ float tile[32][33];
    int g0 = blockIdx.x * 32;
    int b0 = blockIdx.y * 32;
    int tx = threadIdx.x, ty = threadIdx.y;
    tile[ty][tx] = x[(size_t)(b0 + ty) * GENES + (g0 + tx)];
    __syncthreads();
    xT[(size_t)(g0 + ty) * BATCH + (b0 + tx)] = f32_to_bf16_rn(tile[tx][ty]);
}

__global__ void zero_f32(float* __restrict__ p, int n) {
    int i = blockIdx.x * 256 + threadIdx.x;
    if (i < n) p[i] = 0.0f;
}

// ---------------- K1: per-block LDS histogram over (range, tf) bins ----------------
__global__ __launch_bounds__(256) void hist_k(const int* __restrict__ gi,
                                              const int* __restrict__ ti,
                                              int E, int chunk,
                                              int* __restrict__ blkhist) {
    __shared__ int h[NBINS];
    for (int i = threadIdx.x; i < NBINS; i += 256) h[i] = 0;
    __syncthreads();
    int blk = blockIdx.x;
    int lo = blk * chunk;
    int hi = min(lo + chunk, E);
    for (int e = lo + threadIdx.x; e < hi; e += 256) {
        int bin = (gi[e] / GPR) * TFS + ti[e];
        atomicAdd(&h[bin], 1);          // LDS-scope ds_add, cheap
    }
    __syncthreads();
    for (int i = threadIdx.x; i < NBINS; i += 256)
        blkhist[(size_t)blk * NBINS + i] = h[i];   // coalesced
}

// ---------------- K2: per-bin totals ----------------
__global__ void totals_k(const int* __restrict__ blkhist, int* __restrict__ total) {
    int bin = blockIdx.x * 256 + threadIdx.x;
    if (bin >= NBINS) return;
    int s = 0;
    #pragma unroll 4
    for (int b = 0; b < NB; ++b) s += blkhist[(size_t)b * NBINS + bin];  // coalesced per iter
    total[bin] = s;
}

// ---------------- K3: single-block exclusive scan of 12000 bin totals ----------------
__global__ __launch_bounds__(1024) void scan_k(const int* __restrict__ total,
                                               int* __restrict__ bin_start) {
    const int PER = 12;  // 1024*12 = 12288 >= NBINS
    __shared__ int wsum[16];
    int t = threadIdx.x;
    int base = t * PER;
    int loc[PER];
    int s = 0;
    #pragma unroll
    for (int i = 0; i < PER; ++i) {
        int bi = base + i;
        int v = (bi < NBINS) ? total[bi] : 0;
        loc[i] = s;
        s += v;
    }
    int lane = t & 63, wid = t >> 6;
    int inc = s;
    #pragma unroll
    for (int d = 1; d < 64; d <<= 1) {
        int u = __shfl_up(inc, d, 64);
        if (lane >= d) inc += u;
    }
    if (lane == 63) wsum[wid] = inc;
    __syncthreads();
    if (t == 0) {
        int r = 0;
        #pragma unroll
        for (int i = 0; i < 16; ++i) { int v = wsum[i]; wsum[i] = r; r += v; }
    }
    __syncthreads();
    int excl = wsum[wid] + (inc - s);
    #pragma unroll
    for (int i = 0; i < PER; ++i) {
        int bi = base + i;
        if (bi < NBINS) bin_start[bi] = excl + loc[i];
    }
    if (t == 1023) bin_start[NBINS] = excl + s;  // == E
}

// ---------------- K4: in-place per-(block,bin) offsets ----------------
__global__ void blkoff_k(int* __restrict__ blkhist, const int* __restrict__ bin_start) {
    int bin = blockIdx.x * 256 + threadIdx.x;
    if (bin >= NBINS) return;
    int run = bin_start[bin];
    #pragma unroll 4
    for (int b = 0; b < NB; ++b) {
        size_t idx = (size_t)b * NBINS + bin;
        int v = blkhist[idx];
        blkhist[idx] = run;   // becomes blkoff
        run += v;
    }
}

// ---------------- K5: place edges at exact sorted positions (LDS cursors only) ----------------
__global__ __launch_bounds__(256) void place_k(const int* __restrict__ gi,
                                               const int* __restrict__ ti,
                                               const float* __restrict__ w,
                                               int E, int chunk,
                                               const int* __restrict__ blkoff,
                                               unsigned long long* __restrict__ binned) {
    __shared__ int cur[NBINS];
    int blk = blockIdx.x;
    for (int i = threadIdx.x; i < NBINS; i += 256)
        cur[i] = blkoff[(size_t)blk * NBINS + i];
    __syncthreads();
    int lo = blk * chunk;
    int hi = min(lo + chunk, E);
    for (int e = lo + threadIdx.x; e < hi; e += 256) {
        int g = gi[e];
        int bin = (g / GPR) * TFS + ti[e];
        int pos = atomicAdd(&cur[bin], 1);   // ds_add_rtn, LDS-scope
        binned[pos] = ((unsigned long long)__float_as_uint(w[e]) << 32) | (unsigned int)g;
    }
}

// ---------------- compute: block = (grp, tf); grp pins 2 gene-ranges per XCD ----------------
__global__ __launch_bounds__(128) void compute3(
        const unsigned long long* __restrict__ binned,
        const int* __restrict__ bin_start,
        const unsigned short* __restrict__ xT,
        float* __restrict__ out4) {
    int gid = blockIdx.x;
    int grp = gid & 3;      // with XCD = gid%8, XCD k sees grp = k&3 -> slices {2grp,2grp+1}
    int tf  = gid >> 2;
    int tid = threadIdx.x;
    float acc = 0.0f;
    __shared__ unsigned long long lds[256];
    for (int half = 0; half < 2; ++half) {
        int bin = (grp * 2 + half) * TFS + tf;
        int s = bin_start[bin];
        int e = bin_start[bin + 1];
        for (int base = s; base < e; base += 256) {
            int cnt = min(256, e - base);
            __syncthreads();
            for (int i = tid; i < cnt; i += 128) lds[i] = binned[base + i];
            __syncthreads();
            #pragma unroll 8
            for (int i = 0; i < cnt; ++i) {
                unsigned long long p = lds[i];   // uniform address -> LDS broadcast
                int g = (int)(unsigned int)(p & 0xffffffffu);
                float wv = __uint_as_float((unsigned int)(p >> 32));
                float xv = __uint_as_float(((unsigned int)xT[(size_t)g * BATCH + tid]) << 16);
                acc += wv * xv;
            }
        }
    }
    out4[((size_t)grp * TFS + tf) * BATCH + tid] = acc;  // plain store, no atomics
}

// ---------------- transpose + reduce 4 partials: out[b][t] = sum_g out4[g][t][b] ----------------
__global__ void transpose_out4(const float* __restrict__ out4, float* __restrict__ out) {
    __shared__ float tile[32][33];
    int t0 = blockIdx.x * 32;
    int b0 = blockIdx.y * 32;
    int tx = threadIdx.x, ty = threadIdx.y;
    int t = t0 + ty;
    if (t < TFS) {
        float s = 0.0f;
        #pragma unroll
        for (int g2 = 0; g2 < 4; ++g2)
            s += out4[((size_t)g2 * TFS + t) * BATCH + (b0 + tx)];
        tile[ty][tx] = s;
    }
    __syncthreads();
    if (t0 + tx < TFS)
        out[(size_t)(b0 + ty) * TFS + (t0 + tx)] = tile[tx][ty];
}

// ---------------- fallback (ws too small): direct atomics ----------------
__global__ void fallback_kernel(const float* __restrict__ x, const float* __restrict__ w,
                                const int* __restrict__ gi, const int* __restrict__ ti,
                                int E, float* __restrict__ out) {
    long long idx = (long long)blockIdx.x * blockDim.x + threadIdx.x;
    long long total = (long long)E * 64;
    if (idx >= total) return;
    int e = (int)(idx >> 6);
    int b2 = (int)(idx & 63);
    int g = gi[e], t = ti[e];
    float wv = w[e];
    int b0 = b2 * 2;
    atomicAdd(&out[(size_t)b0 * TFS + t], wv * x[(size_t)b0 * GENES + g]);
    atomicAdd(&out[(size_t)(b0 + 1) * TFS + t], wv * x[(size_t)(b0 + 1) * GENES + g]);
}

extern "C" void kernel_launch(void* const* d_in, const int* in_sizes, int n_in,
                              void* d_out, int out_size, void* d_ws, size_t ws_size,
                              hipStream_t stream) {
    const float* x  = (const float*)d_in[0];
    const float* w  = (const float*)d_in[1];
    const int*   gi = (const int*)d_in[2];
    const int*   ti = (const int*)d_in[3];
    float* out = (float*)d_out;
    int E = in_sizes[1];
    int chunk = (E + NB - 1) / NB;

    size_t xT_bytes      = (size_t)GENES * BATCH * 2;            //  5,120,000
    size_t binned_bytes  = ((size_t)E * 8 + 15) & ~(size_t)15;   //  8,000,000
    size_t blkhist_bytes = (size_t)NB * NBINS * 4;               //  3,072,000
    size_t out4_bytes    = (size_t)4 * TFS * BATCH * 4;          //  3,072,000 (aliases blkhist)
    size_t big_bytes     = blkhist_bytes > out4_bytes ? blkhist_bytes : out4_bytes;
    size_t binstart_bytes = ((size_t)(NBINS + 1) * 4 + 15) & ~(size_t)15;
    size_t total_bytes   = (size_t)NBINS * 4;
    size_t need = xT_bytes + binned_bytes + big_bytes + binstart_bytes + total_bytes;
    // ~16.34 MB

    if (ws_size < need) {
        zero_f32<<<(out_size + 255) / 256, 256, 0, stream>>>(out, out_size);
        long long total = (long long)E * 64;
        int blocks = (int)((total + 255) / 256);
        fallback_kernel<<<blocks, 256, 0, stream>>>(x, w, gi, ti, E, out);
        return;
    }

    char* ws = (char*)d_ws;
    unsigned short*     xT        = (unsigned short*)ws;
    unsigned long long* binned    = (unsigned long long*)(ws + xT_bytes);
    int*                blkhist   = (int*)(ws + xT_bytes + binned_bytes);      // later: blkoff, then out4
    float*              out4      = (float*)blkhist;                            // alias: blkhist dead after place_k
    int*                bin_start = (int*)(ws + xT_bytes + binned_bytes + big_bytes);
    int*                total     = (int*)(ws + xT_bytes + binned_bytes + big_bytes + binstart_bytes);

    transpose_x_bf16<<<dim3(GENES / 32, BATCH / 32), dim3(32, 32), 0, stream>>>(x, xT);
    hist_k  <<<NB, 256, 0, stream>>>(gi, ti, E, chunk, blkhist);
    totals_k<<<(NBINS + 255) / 256, 256, 0, stream>>>(blkhist, total);
    scan_k  <<<1, 1024, 0, stream>>>(total, bin_start);
    blkoff_k<<<(NBINS + 255) / 256, 256, 0, stream>>>(blkhist, bin_start);
    place_k <<<NB, 256, 0, stream>>>(gi, ti, w, E, chunk, blkhist, binned);
    compute3<<<TFS * 4, 128, 0, stream>>>(binned, bin_start, xT, out4);
    transpose_out4<<<dim3((TFS + 31) / 32, BATCH / 32), dim3(32, 32), 0, stream>>>(out4, out);
}

// Round 5
// 99.636 us; speedup vs baseline: 1.2601x; 1.2601x over previous
//
#include <hip/hip_runtime.h>
#include <hip/hip_bf16.h>

#define GENES 20000
#define TFS   1500
#define BATCH 128
#define NR    8            // gene ranges (2 per XCD-group)
#define GPR   2500         // genes per range
#define NBINS (NR * TFS)   // 12000

__device__ __forceinline__ unsigned short f32_to_bf16_rn(float f) {
    unsigned int u = __float_as_uint(f);
    u += 0x7fffu + ((u >> 16) & 1u);
    return (unsigned short)(u >> 16);
}

// ---------------- transpose x[B][G] (f32) -> xT[G][B] (bf16 bits) ----------------
__global__ void transpose_x_bf16(const float* __restrict__ x, unsigned short* __restrict__ xT) {
    __shared__ float tile[32][33];
    int g0 = blockIdx.x * 32;
    int b0 = blockIdx.y * 32;
    int tx = threadIdx.x, ty = threadIdx.y;
    tile[ty][tx] = x[(size_t)(b0 + ty) * GENES + (g0 + tx)];
    __syncthreads();
    xT[(size_t)(g0 + ty) * BATCH + (b0 + tx)] = f32_to_bf16_rn(tile[tx][ty]);
}

__global__ void zero_f32(float* __restrict__ p, int n) {
    int i = blockIdx.x * 256 + threadIdx.x;
    if (i < n) p[i] = 0.0f;
}

// ---------------- K1: per-block LDS histogram over (range, tf) bins ----------------
__global__ __launch_bounds__(512) void hist_k(const int* __restrict__ gi,
                                              const int* __restrict__ ti,
                                              int E, int chunk,
                                              int* __restrict__ blkhist) {
    __shared__ int h[NBINS];
    for (int i = threadIdx.x; i < NBINS; i += 512) h[i] = 0;
    __syncthreads();
    int blk = blockIdx.x;
    int lo = blk * chunk;
    int hi = min(lo + chunk, E);
    #pragma unroll 4
    for (int e = lo + threadIdx.x; e < hi; e += 512) {
        int bin = (gi[e] / GPR) * TFS + ti[e];
        atomicAdd(&h[bin], 1);          // LDS-scope ds_add, no return needed
    }
    __syncthreads();
    for (int i = threadIdx.x; i < NBINS; i += 512)
        blkhist[(size_t)blk * NBINS + i] = h[i];   // coalesced
}

// ---------------- K2: per-bin totals ----------------
__global__ void totals_k(const int* __restrict__ blkhist, int nb, int* __restrict__ total) {
    int bin = blockIdx.x * 256 + threadIdx.x;
    if (bin >= NBINS) return;
    int s = 0;
    #pragma unroll 4
    for (int b = 0; b < nb; ++b) s += blkhist[(size_t)b * NBINS + bin];  // coalesced per iter
    total[bin] = s;
}

// ---------------- K3: single-block exclusive scan of 12000 bin totals ----------------
__global__ __launch_bounds__(1024) void scan_k(const int* __restrict__ total,
                                               int* __restrict__ bin_start) {
    const int PER = 12;  // 1024*12 = 12288 >= NBINS
    __shared__ int wsum[16];
    int t = threadIdx.x;
    int base = t * PER;
    int loc[PER];
    int s = 0;
    #pragma unroll
    for (int i = 0; i < PER; ++i) {
        int bi = base + i;
        int v = (bi < NBINS) ? total[bi] : 0;
        loc[i] = s;
        s += v;
    }
    int lane = t & 63, wid = t >> 6;
    int inc = s;
    #pragma unroll
    for (int d = 1; d < 64; d <<= 1) {
        int u = __shfl_up(inc, d, 64);
        if (lane >= d) inc += u;
    }
    if (lane == 63) wsum[wid] = inc;
    __syncthreads();
    if (t == 0) {
        int r = 0;
        #pragma unroll
        for (int i = 0; i < 16; ++i) { int v = wsum[i]; wsum[i] = r; r += v; }
    }
    __syncthreads();
    int excl = wsum[wid] + (inc - s);
    #pragma unroll
    for (int i = 0; i < PER; ++i) {
        int bi = base + i;
        if (bi < NBINS) bin_start[bi] = excl + loc[i];
    }
    if (t == 1023) bin_start[NBINS] = excl + s;  // == E
}

// ---------------- K4: in-place per-(block,bin) offsets ----------------
__global__ void blkoff_k(int* __restrict__ blkhist, int nb, const int* __restrict__ bin_start) {
    int bin = blockIdx.x * 256 + threadIdx.x;
    if (bin >= NBINS) return;
    int run = bin_start[bin];
    #pragma unroll 4
    for (int b = 0; b < nb; ++b) {
        size_t idx = (size_t)b * NBINS + bin;
        int v = blkhist[idx];
        blkhist[idx] = run;   // becomes blkoff
        run += v;
    }
}

// ---------------- K5: place edges at exact sorted positions (LDS cursors only) ----------------
__global__ __launch_bounds__(512) void place_k(const int* __restrict__ gi,
                                               const int* __restrict__ ti,
                                               const float* __restrict__ w,
                                               int E, int chunk,
                                               const int* __restrict__ blkoff,
                                               unsigned long long* __restrict__ binned) {
    __shared__ int cur[NBINS];
    int blk = blockIdx.x;
    for (int i = threadIdx.x; i < NBINS; i += 512)
        cur[i] = blkoff[(size_t)blk * NBINS + i];
    __syncthreads();
    int lo = blk * chunk;
    int hi = min(lo + chunk, E);
    #pragma unroll 4
    for (int e = lo + threadIdx.x; e < hi; e += 512) {
        int g = gi[e];
        int bin = (g / GPR) * TFS + ti[e];
        int pos = atomicAdd(&cur[bin], 1);   // ds_add_rtn, LDS-scope
        binned[pos] = ((unsigned long long)__float_as_uint(w[e]) << 32) | (unsigned int)g;
    }
}

// ---------------- compute: block = (grp, tf); grp pins 2 gene-ranges per XCD ----------------
__global__ __launch_bounds__(128) void compute3(
        const unsigned long long* __restrict__ binned,
        const int* __restrict__ bin_start,
        const unsigned short* __restrict__ xT,
        float* __restrict__ out4) {
    int gid = blockIdx.x;
    int grp = gid & 3;      // with XCD = gid%8, XCD k sees grp = k&3 -> slices {2grp,2grp+1}
    int tf  = gid >> 2;
    int tid = threadIdx.x;
    float acc = 0.0f;
    __shared__ unsigned long long lds[256];
    for (int half = 0; half < 2; ++half) {
        int bin = (grp * 2 + half) * TFS + tf;
        int s = bin_start[bin];
        int e = bin_start[bin + 1];
        for (int base = s; base < e; base += 256) {
            int cnt = min(256, e - base);
            __syncthreads();
            for (int i = tid; i < cnt; i += 128) lds[i] = binned[base + i];
            __syncthreads();
            #pragma unroll 8
            for (int i = 0; i < cnt; ++i) {
                unsigned long long p = lds[i];   // uniform address -> LDS broadcast
                int g = (int)(unsigned int)(p & 0xffffffffu);
                float wv = __uint_as_float((unsigned int)(p >> 32));
                float xv = __uint_as_float(((unsigned int)xT[(size_t)g * BATCH + tid]) << 16);
                acc += wv * xv;
            }
        }
    }
    out4[((size_t)grp * TFS + tf) * BATCH + tid] = acc;  // plain store, no atomics
}

// ---------------- transpose + reduce 4 partials: out[b][t] = sum_g out4[g][t][b] ----------------
__global__ void transpose_out4(const float* __restrict__ out4, float* __restrict__ out) {
    __shared__ float tile[32][33];
    int t0 = blockIdx.x * 32;
    int b0 = blockIdx.y * 32;
    int tx = threadIdx.x, ty = threadIdx.y;
    int t = t0 + ty;
    if (t < TFS) {
        float s = 0.0f;
        #pragma unroll
        for (int g2 = 0; g2 < 4; ++g2)
            s += out4[((size_t)g2 * TFS + t) * BATCH + (b0 + tx)];
        tile[ty][tx] = s;
    }
    __syncthreads();
    if (t0 + tx < TFS)
        out[(size_t)(b0 + ty) * TFS + (t0 + tx)] = tile[tx][ty];
}

// ---------------- fallback (ws too small): direct atomics ----------------
__global__ void fallback_kernel(const float* __restrict__ x, const float* __restrict__ w,
                                const int* __restrict__ gi, const int* __restrict__ ti,
                                int E, float* __restrict__ out) {
    long long idx = (long long)blockIdx.x * blockDim.x + threadIdx.x;
    long long total = (long long)E * 64;
    if (idx >= total) return;
    int e = (int)(idx >> 6);
    int b2 = (int)(idx & 63);
    int g = gi[e], t = ti[e];
    float wv = w[e];
    int b0 = b2 * 2;
    atomicAdd(&out[(size_t)b0 * TFS + t], wv * x[(size_t)b0 * GENES + g]);
    atomicAdd(&out[(size_t)(b0 + 1) * TFS + t], wv * x[(size_t)(b0 + 1) * GENES + g]);
}

extern "C" void kernel_launch(void* const* d_in, const int* in_sizes, int n_in,
                              void* d_out, int out_size, void* d_ws, size_t ws_size,
                              hipStream_t stream) {
    const float* x  = (const float*)d_in[0];
    const float* w  = (const float*)d_in[1];
    const int*   gi = (const int*)d_in[2];
    const int*   ti = (const int*)d_in[3];
    float* out = (float*)d_out;
    int E = in_sizes[1];

    size_t xT_bytes       = (size_t)GENES * BATCH * 2;            //  5,120,000
    size_t binned_bytes   = ((size_t)E * 8 + 15) & ~(size_t)15;   //  8,000,000
    size_t out4_bytes     = (size_t)4 * TFS * BATCH * 4;          //  3,072,000
    size_t binstart_bytes = ((size_t)(NBINS + 1) * 4 + 15) & ~(size_t)15;
    size_t total_bytes    = (size_t)NBINS * 4;
    size_t fixed = xT_bytes + binned_bytes + binstart_bytes + total_bytes;

    // NB ladder: prefer more sort blocks (parallelism) if workspace allows
    int nb = 0;
    size_t big_bytes = 0;
    const int ladder[3] = {256, 128, 64};
    for (int k = 0; k < 3; ++k) {
        size_t bh = (size_t)ladder[k] * NBINS * 4;
        if (bh < out4_bytes) bh = out4_bytes;
        if (fixed + bh <= ws_size) { nb = ladder[k]; big_bytes = bh; break; }
    }

    if (nb == 0) {
        zero_f32<<<(out_size + 255) / 256, 256, 0, stream>>>(out, out_size);
        long long total = (long long)E * 64;
        int blocks = (int)((total + 255) / 256);
        fallback_kernel<<<blocks, 256, 0, stream>>>(x, w, gi, ti, E, out);
        return;
    }

    int chunk = (E + nb - 1) / nb;

    char* ws = (char*)d_ws;
    unsigned short*     xT        = (unsigned short*)ws;
    unsigned long long* binned    = (unsigned long long*)(ws + xT_bytes);
    int*                blkhist   = (int*)(ws + xT_bytes + binned_bytes);  // later: blkoff, then out4
    float*              out4      = (float*)blkhist;                        // alias: blkhist dead after place_k
    int*                bin_start = (int*)(ws + xT_bytes + binned_bytes + big_bytes);
    int*                total     = (int*)(ws + xT_bytes + binned_bytes + big_bytes + binstart_bytes);

    transpose_x_bf16<<<dim3(GENES / 32, BATCH / 32), dim3(32, 32), 0, stream>>>(x, xT);
    hist_k  <<<nb, 512, 0, stream>>>(gi, ti, E, chunk, blkhist);
    totals_k<<<(NBINS + 255) / 256, 256, 0, stream>>>(blkhist, nb, total);
    scan_k  <<<1, 1024, 0, stream>>>(total, bin_start);
    blkoff_k<<<(NBINS + 255) / 256, 256, 0, stream>>>(blkhist, nb, bin_start);
    place_k <<<nb, 512, 0, stream>>>(gi, ti, w, E, chunk, blkhist, binned);
    compute3<<<TFS * 4, 128, 0, stream>>>(binned, bin_start, xT, out4);
    transpose_out4<<<dim3((TFS + 31) / 32, BATCH / 32), dim3(32, 32), 0, stream>>>(out4, out);
}

// Round 6
// 89.137 us; speedup vs baseline: 1.4085x; 1.1178x over previous
//
#include <hip/hip_runtime.h>
#include <hip/hip_bf16.h>

#define GENES 20000
#define TFS   1500
#define BATCH 128
#define NR    8            // gene ranges (1 per XCD)
#define GPR   2500         // genes per range
#define NBINS (NR * TFS)   // 12000

__device__ __forceinline__ unsigned short f32_to_bf16_rn(float f) {
    unsigned int u = __float_as_uint(f);
    u += 0x7fffu + ((u >> 16) & 1u);
    return (unsigned short)(u >> 16);
}

// ---------------- transpose x[B][G] (f32) -> xT[G][B] (bf16 bits) ----------------
__global__ void transpose_x_bf16(const float* __restrict__ x, unsigned short* __restrict__ xT) {
    __shared__ float tile[32][33];
    int g0 = blockIdx.x * 32;
    int b0 = blockIdx.y * 32;
    int tx = threadIdx.x, ty = threadIdx.y;
    tile[ty][tx] = x[(size_t)(b0 + ty) * GENES + (g0 + tx)];
    __syncthreads();
    xT[(size_t)(g0 + ty) * BATCH + (b0 + tx)] = f32_to_bf16_rn(tile[tx][ty]);
}

__global__ void zero_f32(float* __restrict__ p, int n) {
    int i = blockIdx.x * 256 + threadIdx.x;
    if (i < n) p[i] = 0.0f;
}

// ---------------- K1: per-block LDS histogram over (range, tf) bins ----------------
__global__ __launch_bounds__(512) void hist_k(const int* __restrict__ gi,
                                              const int* __restrict__ ti,
                                              int E, int chunk,
                                              int* __restrict__ blkhist) {
    __shared__ int h[NBINS];
    for (int i = threadIdx.x; i < NBINS; i += 512) h[i] = 0;
    __syncthreads();
    int blk = blockIdx.x;
    int lo = blk * chunk;
    int hi = min(lo + chunk, E);
    #pragma unroll 4
    for (int e = lo + threadIdx.x; e < hi; e += 512) {
        int bin = (gi[e] / GPR) * TFS + ti[e];
        atomicAdd(&h[bin], 1);          // LDS-scope ds_add
    }
    __syncthreads();
    for (int i = threadIdx.x; i < NBINS; i += 512)
        blkhist[(size_t)blk * NBINS + i] = h[i];   // coalesced
}

// ---------------- K2: per-bin column prefix (in place) + totals ----------------
__global__ void prefix1_k(int* __restrict__ blkhist, int nb, int* __restrict__ total) {
    int bin = blockIdx.x * 256 + threadIdx.x;
    if (bin >= NBINS) return;
    int run = 0;
    #pragma unroll 4
    for (int b = 0; b < nb; ++b) {
        size_t idx = (size_t)b * NBINS + bin;
        int v = blkhist[idx];
        blkhist[idx] = run;   // local exclusive prefix (bin_start added in place_k)
        run += v;
    }
    total[bin] = run;
}

// ---------------- K3: single-block exclusive scan of 12000 bin totals ----------------
__global__ __launch_bounds__(1024) void scan_k(const int* __restrict__ total,
                                               int* __restrict__ bin_start) {
    const int PER = 12;  // 1024*12 = 12288 >= NBINS
    __shared__ int wsum[16];
    int t = threadIdx.x;
    int base = t * PER;
    int loc[PER];
    int s = 0;
    #pragma unroll
    for (int i = 0; i < PER; ++i) {
        int bi = base + i;
        int v = (bi < NBINS) ? total[bi] : 0;
        loc[i] = s;
        s += v;
    }
    int lane = t & 63, wid = t >> 6;
    int inc = s;
    #pragma unroll
    for (int d = 1; d < 64; d <<= 1) {
        int u = __shfl_up(inc, d, 64);
        if (lane >= d) inc += u;
    }
    if (lane == 63) wsum[wid] = inc;
    __syncthreads();
    if (t == 0) {
        int r = 0;
        #pragma unroll
        for (int i = 0; i < 16; ++i) { int v = wsum[i]; wsum[i] = r; r += v; }
    }
    __syncthreads();
    int excl = wsum[wid] + (inc - s);
    #pragma unroll
    for (int i = 0; i < PER; ++i) {
        int bi = base + i;
        if (bi < NBINS) bin_start[bi] = excl + loc[i];
    }
    if (t == 1023) bin_start[NBINS] = excl + s;  // == E
}

// ---------------- K4: place edges at exact sorted positions (LDS cursors only) ----------------
__global__ __launch_bounds__(512) void place_k(const int* __restrict__ gi,
                                               const int* __restrict__ ti,
                                               const float* __restrict__ w,
                                               int E, int chunk,
                                               const int* __restrict__ blkoff,
                                               const int* __restrict__ bin_start,
                                               unsigned long long* __restrict__ binned) {
    __shared__ int cur[NBINS];
    int blk = blockIdx.x;
    for (int i = threadIdx.x; i < NBINS; i += 512)
        cur[i] = blkoff[(size_t)blk * NBINS + i] + bin_start[i];
    __syncthreads();
    int lo = blk * chunk;
    int hi = min(lo + chunk, E);
    #pragma unroll 4
    for (int e = lo + threadIdx.x; e < hi; e += 512) {
        int g = gi[e];
        int bin = (g / GPR) * TFS + ti[e];
        int pos = atomicAdd(&cur[bin], 1);   // ds_add_rtn, LDS-scope
        binned[pos] = ((unsigned long long)__float_as_uint(w[e]) << 32) | (unsigned int)g;
    }
}

// ---------------- K5: one bin per 64-thread block; thread owns 2 batch cols ----------------
// gid&7 = range r -> XCD r under round-robin; out8[r][tf][B] plain stores
__global__ __launch_bounds__(64) void compute4(
        const unsigned long long* __restrict__ binned,
        const int* __restrict__ bin_start,
        const unsigned short* __restrict__ xT,
        float* __restrict__ out8) {
    int gid = blockIdx.x;
    int r  = gid & 7;
    int tf = gid >> 3;
    int bin = r * TFS + tf;
    int s = bin_start[bin];
    int e = bin_start[bin + 1];
    int tid = threadIdx.x;
    float acc0 = 0.0f, acc1 = 0.0f;
    __shared__ unsigned long long lds[192];
    for (int base = s; base < e; base += 192) {
        int cnt = min(192, e - base);
        __syncthreads();
        for (int i = tid; i < cnt; i += 64) lds[i] = binned[base + i];
        __syncthreads();
        #pragma unroll 8
        for (int i = 0; i < cnt; ++i) {
            unsigned long long p = lds[i];   // uniform address -> LDS broadcast
            int g = (int)(unsigned int)(p & 0xffffffffu);
            float wv = __uint_as_float((unsigned int)(p >> 32));
            unsigned int xx = *(const unsigned int*)&xT[(size_t)g * BATCH + 2 * tid];
            float x0 = __uint_as_float(xx << 16);
            float x1 = __uint_as_float(xx & 0xffff0000u);
            acc0 += wv * x0;
            acc1 += wv * x1;
        }
    }
    float2 st; st.x = acc0; st.y = acc1;
    *(float2*)&out8[((size_t)bin) * BATCH + 2 * tid] = st;
}

// ---------------- transpose + reduce 8 partials: out[b][t] = sum_r out8[r][t][b] ----------------
__global__ void transpose_out8(const float* __restrict__ out8, float* __restrict__ out) {
    __shared__ float tile[32][33];
    int t0 = blockIdx.x * 32;
    int b0 = blockIdx.y * 32;
    int tx = threadIdx.x, ty = threadIdx.y;
    int t = t0 + ty;
    if (t < TFS) {
        float s = 0.0f;
        #pragma unroll
        for (int r = 0; r < NR; ++r)
            s += out8[((size_t)r * TFS + t) * BATCH + (b0 + tx)];
        tile[ty][tx] = s;
    }
    __syncthreads();
    if (t0 + tx < TFS)
        out[(size_t)(b0 + ty) * TFS + (t0 + tx)] = tile[tx][ty];
}

// ---------------- fallback (ws too small): direct atomics ----------------
__global__ void fallback_kernel(const float* __restrict__ x, const float* __restrict__ w,
                                const int* __restrict__ gi, const int* __restrict__ ti,
                                int E, float* __restrict__ out) {
    long long idx = (long long)blockIdx.x * blockDim.x + threadIdx.x;
    long long total = (long long)E * 64;
    if (idx >= total) return;
    int e = (int)(idx >> 6);
    int b2 = (int)(idx & 63);
    int g = gi[e], t = ti[e];
    float wv = w[e];
    int b0 = b2 * 2;
    atomicAdd(&out[(size_t)b0 * TFS + t], wv * x[(size_t)b0 * GENES + g]);
    atomicAdd(&out[(size_t)(b0 + 1) * TFS + t], wv * x[(size_t)(b0 + 1) * GENES + g]);
}

extern "C" void kernel_launch(void* const* d_in, const int* in_sizes, int n_in,
                              void* d_out, int out_size, void* d_ws, size_t ws_size,
                              hipStream_t stream) {
    const float* x  = (const float*)d_in[0];
    const float* w  = (const float*)d_in[1];
    const int*   gi = (const int*)d_in[2];
    const int*   ti = (const int*)d_in[3];
    float* out = (float*)d_out;
    int E = in_sizes[1];

    size_t xT_bytes       = (size_t)GENES * BATCH * 2;            //  5,120,000
    size_t binned_bytes   = ((size_t)E * 8 + 15) & ~(size_t)15;   //  8,000,000
    size_t out8_bytes     = (size_t)NR * TFS * BATCH * 4;         //  6,144,000
    size_t binstart_bytes = ((size_t)(NBINS + 1) * 4 + 15) & ~(size_t)15;
    size_t total_bytes    = (size_t)NBINS * 4;
    size_t fixed = xT_bytes + binned_bytes + binstart_bytes + total_bytes;

    // NB ladder: prefer more sort blocks (parallelism) if workspace allows
    int nb = 0;
    size_t big_bytes = 0;
    const int ladder[3] = {256, 128, 64};
    for (int k = 0; k < 3; ++k) {
        size_t bh = (size_t)ladder[k] * NBINS * 4;
        if (bh < out8_bytes) bh = out8_bytes;
        if (fixed + bh <= ws_size) { nb = ladder[k]; big_bytes = bh; break; }
    }

    if (nb == 0) {
        zero_f32<<<(out_size + 255) / 256, 256, 0, stream>>>(out, out_size);
        long long total = (long long)E * 64;
        int blocks = (int)((total + 255) / 256);
        fallback_kernel<<<blocks, 256, 0, stream>>>(x, w, gi, ti, E, out);
        return;
    }

    int chunk = (E + nb - 1) / nb;

    char* ws = (char*)d_ws;
    unsigned short*     xT        = (unsigned short*)ws;
    unsigned long long* binned    = (unsigned long long*)(ws + xT_bytes);
    int*                blkhist   = (int*)(ws + xT_bytes + binned_bytes);  // later out8 aliases
    float*              out8      = (float*)blkhist;                        // blkhist dead after place_k
    int*                bin_start = (int*)(ws + xT_bytes + binned_bytes + big_bytes);
    int*                total     = (int*)(ws + xT_bytes + binned_bytes + big_bytes + binstart_bytes);

    transpose_x_bf16<<<dim3(GENES / 32, BATCH / 32), dim3(32, 32), 0, stream>>>(x, xT);
    hist_k   <<<nb, 512, 0, stream>>>(gi, ti, E, chunk, blkhist);
    prefix1_k<<<(NBINS + 255) / 256, 256, 0, stream>>>(blkhist, nb, total);
    scan_k   <<<1, 1024, 0, stream>>>(total, bin_start);
    place_k  <<<nb, 512, 0, stream>>>(gi, ti, w, E, chunk, blkhist, bin_start, binned);
    compute4 <<<NBINS, 64, 0, stream>>>(binned, bin_start, xT, out8);
    transpose_out8<<<dim3((TFS + 31) / 32, BATCH / 32), dim3(32, 32), 0, stream>>>(out8, out);
}